// Round 14
// baseline (129.002 us; speedup 1.0000x reference)
//
#include <hip/hip_runtime.h>
#include <hip/hip_fp16.h>
#include <math.h>

// MatchAttention fused forward — fp16-packed kv, 16 lanes/pixel-head,
// lane-parity k/v specialization, backedge-pipelined rows.
// B=2, H=W=64 (N=4096), C=256, h=8 (Ch=32), 7x7=49 window.
//
// Ledger: R11 (49 vs 98 gathers: +15%) ruled out instruction-throughput;
// R8-R13 occupancy pinned at ~30% (VGPR ~150 w/ 56-reg double buffer)
// rules latency hiding capped by RESIDENCY. Trade: 16 lanes x 8B per
// pixel-head line (even lanes k-chunks, odd lanes v-chunks — the packed
// [k4|v4]x8 layout already interleaves). Per-thread state halves ->
// ~2-3x resident waves; wave count doubles (16384 = 64/CU).
constexpr int B = 2, H = 64, W = 64, C = 256, NH = 8, CH = 32;
constexpr int R = 3, KW = 7, KK = 49, N = H * W;

template <int CTRL>
static __device__ __forceinline__ float dpp_mov(float v) {
  union { float f; int i; } u;
  u.f = v;
  u.i = __builtin_amdgcn_update_dpp(u.i, u.i, CTRL, 0xf, 0xf, true);
  return u.f;
}
#define DPP_QUAD_XOR1 0xB1     // quad_perm [1,0,3,2]
#define DPP_QUAD_XOR2 0x4E     // quad_perm [2,3,0,1]
#define DPP_HALF_MIRROR 0x141  // i -> i^7 within 8-lane half-rows
#define DPP_ROW_MIRROR 0x140   // i -> 15-i within 16-lane rows (cross-8)

// pack k,v fp32 -> fp16 interleaved: [b][n][g][(k0..3 v0..3) x 8] = 128B
__global__ void __launch_bounds__(256) pack_kv_kernel(
    const float* __restrict__ kp, const float* __restrict__ vp,
    __half* __restrict__ kv) {
  const int idx = blockIdx.x * 256 + threadIdx.x;  // 0..524287
  const int e8 = idx & 7;
  const int g = (idx >> 3) & 7;
  const int bn = idx >> 6;  // 0..8191 = b*N+n
  const float4 kf = *(const float4*)(kp + (size_t)bn * C + g * CH + e8 * 4);
  const float4 vf = *(const float4*)(vp + (size_t)bn * C + g * CH + e8 * 4);
  __half2 o[4];
  o[0] = __floats2half2_rn(kf.x, kf.y);
  o[1] = __floats2half2_rn(kf.z, kf.w);
  o[2] = __floats2half2_rn(vf.x, vf.y);
  o[3] = __floats2half2_rn(vf.z, vf.w);
  *(float4*)(kv + ((size_t)(bn * NH + g) * 64 + e8 * 8)) = *(float4*)o;
}

union KV8 { float2 f; __half2 h[2]; };  // one 8B granule (k4 or v4 halves)

__global__ void __launch_bounds__(256, 2) match_attn_kernel(
    const float* __restrict__ moff, const float* __restrict__ qp,
    const __half* __restrict__ kvp, float* __restrict__ outp,
    float* __restrict__ attnp) {
  const int t = threadIdx.x;
  const int e16 = t & 15;           // lane within pixel-head group
  const int p = t >> 4;             // pixel-head within block, 0..15
  const bool klane = !(e16 & 1);    // even lanes hold k, odd hold v
  const int chunk = e16 >> 1;       // 4-channel chunk 0..7

  // XCD swizzle: blk&7 ~ XCD; XCD x owns (b,g) pairs {2x,2x+1}
  const int xcd = blockIdx.x & 7;
  const int rest = blockIdx.x >> 3;      // 0..511
  const int bg = xcd * 2 + (rest >> 8);  // 0..15
  const int slot = rest & 255;           // (y, quarter-row)
  const int y = slot >> 2;
  const int x = (slot & 3) * 16 + p;
  const int g = bg & 7;
  const int b = bg >> 3;
  const int n = y * W + x;

  // per-pixel, per-head rounded (dy,dx); rintf == jnp.round (half-to-even)
  const float2 off = *(const float2*)(moff + ((size_t)(b * N + n) * NH + g) * 2);
  const int cy = y + (int)rintf(off.x);
  const int cx = x + (int)rintf(off.y);

  // clamped x offsets in BYTES (pixel stride 1024B); y offset on the fly
  int pxo[KW];
#pragma unroll
  for (int i = 0; i < KW; ++i) pxo[i] = min(max(cx + i - R, 0), W - 1) << 10;
  // per-lane gather base: b image + head + lane granule (8B)
  const char* kvimg = (const char*)kvp +
      (size_t)b * N * NH * 128 + g * 128 + e16 * 8;

  const int chn = g * CH + chunk * 4;
  const float4 q0 = *(const float4*)(qp + (size_t)(b * N + n) * C + chn);
  const __half2 q01 = __floats2half2_rn(q0.x, q0.y);
  const __half2 q23 = __floats2half2_rn(q0.z, q0.w);

  float ev7[KW];  // attn weights of row e16 (lanes 0..6 own rows 0..6)
#pragma unroll
  for (int i = 0; i < KW; ++i) ev7[i] = 0.f;
  float4 acc = {0.f, 0.f, 0.f, 0.f};  // odd lanes: unnormalized e*v sum
  float d0 = 0.f, d1 = 0.f;           // two denom chains

#define ROWOFF(iy) (min(max(cy + (iy) - R, 0), H - 1) << 16)
#define LOADROW(buf, iy)                                            \
  {                                                                 \
    const int _ro = ROWOFF(iy);                                     \
    _Pragma("unroll") for (int ix = 0; ix < KW; ++ix)               \
        buf[ix].f = *(const float2*)(kvimg + (_ro + pxo[ix]));      \
  }
#define COMPROW(buf, iy)                                            \
  {                                                                 \
    const bool _own = ((iy) == e16);                                \
    _Pragma("unroll") for (int ix = 0; ix < KW; ++ix) {             \
      const __half2 a01 = __habs2(__hsub2(q01, buf[ix].h[0]));      \
      const __half2 a23 = __habs2(__hsub2(q23, buf[ix].h[1]));      \
      const float2 f01 = __half22float2(a01);                       \
      const float2 f23 = __half22float2(a23);                       \
      float s = (f01.x + f01.y) + (f23.x + f23.y);                  \
      if (!klane) s = 0.f; /* v-lanes contribute 0 to the L1 sum */ \
      s += dpp_mov<DPP_QUAD_XOR1>(s);                               \
      s += dpp_mov<DPP_QUAD_XOR2>(s);                               \
      s += dpp_mov<DPP_HALF_MIRROR>(s);                             \
      s += dpp_mov<DPP_ROW_MIRROR>(s);                              \
      const float e = __expf(-s); /* sim<=0: no max-shift needed */ \
      if (ix & 1) d1 += e; else d0 += e;                            \
      if (_own) ev7[ix] = e;                                        \
      const float2 v01 = __half22float2(buf[ix].h[0]);              \
      const float2 v23 = __half22float2(buf[ix].h[1]);              \
      acc.x += e * v01.x; acc.y += e * v01.y;  /* garbage on k-lanes, */ \
      acc.z += e * v23.x; acc.w += e * v23.y;  /* discarded at store  */ \
    }                                                               \
  }

  KV8 A[KW], Bf[KW];
  LOADROW(A, 0)  // prologue: row 0 in flight
#pragma clang loop unroll(disable)
  for (int ty = 0; ty < KW - 1; ty += 2) {  // runtime backedge: loads for
    LOADROW(Bf, ty + 1)   // row ty+1 / ty+2 stay in flight across compute
    COMPROW(A, ty)
    LOADROW(A, ty + 2)
    COMPROW(Bf, ty + 1)
  }
  COMPROW(A, KW - 1)      // epilogue: row 6

  const float inv = 1.0f / (d0 + d1);
  // odd (v) lanes store their 4 output channels: 8 lanes cover the head
  if (!klane) {
    float4 o;
    o.x = acc.x * inv; o.y = acc.y * inv;
    o.z = acc.z * inv; o.w = acc.w * inv;
    *(float4*)(outp + (size_t)(b * N + n) * C + chn) = o;
  }
  // lanes 0..6 write window row e16 of attn, normalized, exactly once
  if (e16 < KW) {
    float* attn_row = attnp + ((size_t)(b * N + n) * NH + g) * KK + e16 * KW;
#pragma unroll
    for (int ix = 0; ix < KW; ++ix) attn_row[ix] = ev7[ix] * inv;
  }
}

extern "C" void kernel_launch(void* const* d_in, const int* in_sizes, int n_in,
                              void* d_out, int out_size, void* d_ws, size_t ws_size,
                              hipStream_t stream) {
  const float* moff = (const float*)d_in[0];  // [B,N,h,2]
  const float* q    = (const float*)d_in[1];  // [B,N,C]
  const float* k    = (const float*)d_in[2];  // [B,N,C]
  const float* v    = (const float*)d_in[3];  // [B,N,C]
  float* out  = (float*)d_out;            // [B,N,C]
  float* attn = out + (size_t)B * N * C;  // [B,N,h,K]
  __half* kv = (__half*)d_ws;             // packed fp16 kv, 8.4 MB

  pack_kv_kernel<<<B * N * NH * 8 / 256, 256, 0, stream>>>(k, v, kv);
  const int grid = B * NH * N / 16;  // 4096 blocks: 16 pixel-heads each
  match_attn_kernel<<<grid, 256, 0, stream>>>(moff, q, kv, out, attn);
}